// Round 1
// baseline (481.180 us; speedup 1.0000x reference)
//
#include <hip/hip_runtime.h>
#include <math.h>

#define PI2F 6.28318530717958647692f

// M[r,c] of the 4096-point naive-cas "FHT" operator defined by the reference
// recursion: X[k] = E[k] + cas(2pi k/n) O[k]; X[k+n/2] = E[k] - cas(...) O[k].
// Bit l of c selects the odd branch at level l (size 4096>>l).
__device__ __forceinline__ float mval(int r, int c) {
    float prod = 1.0f;
    int m = r;
#pragma unroll
    for (int l = 0; l < 12; ++l) {
        const int nl = 4096 >> l;
        const int half = nl >> 1;
        float sign = 1.0f;
        if (m >= half) { m -= half; sign = -1.0f; }
        if ((c >> l) & 1) {
            float th = (PI2F / (float)nl) * (float)m;
            float s, cc;
            sincosf(th, &s, &cc);
            prod *= sign * (cc + s);
        }
    }
    return prod;
}

// MrT[j][m] = M[m][j]  (analysis rows, m<64), Mc[n][m] = M[n][m]/4096 (synthesis cols)
__global__ void matgen(float* __restrict__ MrT, float* __restrict__ Mc) {
    const int j = blockIdx.x;    // 0..4095
    const int m = threadIdx.x;   // 0..63
    MrT[j * 64 + m] = mval(m, j);
    Mc[j * 64 + m]  = mval(j, m) * (1.0f / 4096.0f);
}

// wp[m][i][o] = 0.5*(w[i][o][m] + w[i][o][m']), wm = 0.5*(w - w'), m'=(64-m)%64
__global__ void wtrans(const float* __restrict__ w,
                       float* __restrict__ wp, float* __restrict__ wm) {
    const int i = blockIdx.x;    // 0..127
    const int m = blockIdx.y;    // 0..63
    const int o = threadIdx.x;   // 0..127
    const int mp = (64 - m) & 63;
    const float a = w[(i * 128 + o) * 64 + m];
    const float b = w[(i * 128 + o) * 64 + mp];
    wp[((size_t)m * 128 + i) * 128 + o] = 0.5f * (a + b);
    wm[((size_t)m * 128 + i) * 128 + o] = 0.5f * (a - b);
}

// Pass A: xh_t[m][row] += sum_j X[row][j] * MrT[j][m], row=(b*128+i)
// Tile: 128 rows x 64 m, K-slice 512 per block (grid 64 x 8), atomics combine slices.
__global__ __launch_bounds__(256) void passA(const float* __restrict__ X,
                                             const float* __restrict__ MrT,
                                             float* __restrict__ xh_t) {
    __shared__ float Xs[64][132];   // [k][row], pad for store conflicts
    __shared__ float Ms[64][64];    // [k][m]
    const int tid = threadIdx.x;
    const int rBase = blockIdx.x * 128;
    const int kSlice = blockIdx.y * 512;
    const int r0 = (tid & 15) * 8;
    const int m0 = (tid >> 4) * 4;

    float acc[8][4];
#pragma unroll
    for (int a = 0; a < 8; ++a)
#pragma unroll
        for (int b = 0; b < 4; ++b) acc[a][b] = 0.0f;

    for (int ch = 0; ch < 8; ++ch) {
        const int kc = kSlice + ch * 64;
#pragma unroll
        for (int it = 0; it < 8; ++it) {
            const int slot = tid + it * 256;       // 2048 float4 slots
            const int row = slot >> 4;
            const int j4 = slot & 15;
            const float4 v = *(const float4*)(X + (size_t)(rBase + row) * 4096 + kc + j4 * 4);
            Xs[j4 * 4 + 0][row] = v.x;
            Xs[j4 * 4 + 1][row] = v.y;
            Xs[j4 * 4 + 2][row] = v.z;
            Xs[j4 * 4 + 3][row] = v.w;
        }
#pragma unroll
        for (int it = 0; it < 4; ++it) {
            const int slot = tid + it * 256;       // 1024 float4 slots
            const int k = slot >> 4;
            const int m4 = slot & 15;
            *(float4*)&Ms[k][m4 * 4] =
                *(const float4*)(MrT + (size_t)(kc + k) * 64 + m4 * 4);
        }
        __syncthreads();
#pragma unroll 8
        for (int k = 0; k < 64; ++k) {
            float a[8], b[4];
            *(float4*)&a[0] = *(const float4*)&Xs[k][r0];
            *(float4*)&a[4] = *(const float4*)&Xs[k][r0 + 4];
            *(float4*)&b[0] = *(const float4*)&Ms[k][m0];
#pragma unroll
            for (int jr = 0; jr < 8; ++jr)
#pragma unroll
                for (int jm = 0; jm < 4; ++jm)
                    acc[jr][jm] += a[jr] * b[jm];
        }
        __syncthreads();
    }
#pragma unroll
    for (int jm = 0; jm < 4; ++jm)
#pragma unroll
        for (int jr = 0; jr < 8; ++jr)
            atomicAdd(&xh_t[(size_t)(m0 + jm) * 8192 + rBase + r0 + jr], acc[jr][jm]);
}

// Pass B: mixed_t[m][b*128+o] = sum_i Us[b][i]*wp[m][i][o] + Uns[b][i]*wm[m][i][o]
// grid (4 i-slices, 64 m); atomics combine i-slices.
__global__ __launch_bounds__(256) void passB(const float* __restrict__ xh_t,
                                             const float* __restrict__ wp,
                                             const float* __restrict__ wm,
                                             float* __restrict__ mixed_t) {
    __shared__ float Us[64][33];
    __shared__ float Uns[64][33];
    const int tid = threadIdx.x;
    const int m = blockIdx.y;
    const int iBase = blockIdx.x * 32;
    const int mp = (64 - m) & 63;
#pragma unroll
    for (int it = 0; it < 2; ++it) {
        const int slot = tid + it * 256;   // 512 float4 slots
        const int b = slot >> 3;
        const int i4 = slot & 7;
        const float4 vu = *(const float4*)(xh_t + (size_t)m * 8192 + b * 128 + iBase + i4 * 4);
        const float4 vn = *(const float4*)(xh_t + (size_t)mp * 8192 + b * 128 + iBase + i4 * 4);
        Us[b][i4 * 4 + 0] = vu.x; Us[b][i4 * 4 + 1] = vu.y;
        Us[b][i4 * 4 + 2] = vu.z; Us[b][i4 * 4 + 3] = vu.w;
        Uns[b][i4 * 4 + 0] = vn.x; Uns[b][i4 * 4 + 1] = vn.y;
        Uns[b][i4 * 4 + 2] = vn.z; Uns[b][i4 * 4 + 3] = vn.w;
    }
    __syncthreads();
    const int o0 = (tid & 15) * 8;
    const int b0 = (tid >> 4) * 4;
    float acc[4][8];
#pragma unroll
    for (int a = 0; a < 4; ++a)
#pragma unroll
        for (int b = 0; b < 8; ++b) acc[a][b] = 0.0f;

    for (int i = 0; i < 32; ++i) {
        const int ig = iBase + i;
        float p[8], q[8];
        *(float4*)&p[0] = *(const float4*)(wp + ((size_t)m * 128 + ig) * 128 + o0);
        *(float4*)&p[4] = *(const float4*)(wp + ((size_t)m * 128 + ig) * 128 + o0 + 4);
        *(float4*)&q[0] = *(const float4*)(wm + ((size_t)m * 128 + ig) * 128 + o0);
        *(float4*)&q[4] = *(const float4*)(wm + ((size_t)m * 128 + ig) * 128 + o0 + 4);
#pragma unroll
        for (int jb = 0; jb < 4; ++jb) {
            const float u = Us[b0 + jb][i];
            const float un = Uns[b0 + jb][i];
#pragma unroll
            for (int jo = 0; jo < 8; ++jo)
                acc[jb][jo] += u * p[jo] + un * q[jo];
        }
    }
#pragma unroll
    for (int jb = 0; jb < 4; ++jb)
#pragma unroll
        for (int jo = 0; jo < 8; ++jo)
            atomicAdd(&mixed_t[(size_t)m * 8192 + (b0 + jb) * 128 + o0 + jo], acc[jb][jo]);
}

// Pass C: out[row][n] = sum_{m<64} mixed_t[m][row] * Mc[n][m]   (1/4096 folded into Mc)
// Tile 128 rows x 128 n, K=64. grid (32 nTiles, 64 rowTiles).
__global__ __launch_bounds__(256) void passC(const float* __restrict__ mixed_t,
                                             const float* __restrict__ Mc,
                                             float* __restrict__ out) {
    __shared__ float As[64][128];   // [m][row]
    __shared__ float Bs[64][132];   // [m][n]
    const int tid = threadIdx.x;
    const int nBase = blockIdx.x * 128;
    const int rBase = blockIdx.y * 128;
#pragma unroll
    for (int it = 0; it < 8; ++it) {
        const int slot = tid + it * 256;   // 2048 float4 slots
        const int mm = slot >> 5;
        const int c4 = slot & 31;
        *(float4*)&As[mm][c4 * 4] =
            *(const float4*)(mixed_t + (size_t)mm * 8192 + rBase + c4 * 4);
    }
#pragma unroll
    for (int it = 0; it < 8; ++it) {
        const int slot = tid + it * 256;
        const int n = slot >> 4;
        const int m4 = slot & 15;
        const float4 v = *(const float4*)(Mc + (size_t)(nBase + n) * 64 + m4 * 4);
        Bs[m4 * 4 + 0][n] = v.x;
        Bs[m4 * 4 + 1][n] = v.y;
        Bs[m4 * 4 + 2][n] = v.z;
        Bs[m4 * 4 + 3][n] = v.w;
    }
    __syncthreads();
    const int r0 = (tid & 15) * 8;
    const int n0 = (tid >> 4) * 8;
    float acc[8][8];
#pragma unroll
    for (int a = 0; a < 8; ++a)
#pragma unroll
        for (int b = 0; b < 8; ++b) acc[a][b] = 0.0f;

#pragma unroll 4
    for (int k = 0; k < 64; ++k) {
        float a[8], b[8];
        *(float4*)&a[0] = *(const float4*)&As[k][r0];
        *(float4*)&a[4] = *(const float4*)&As[k][r0 + 4];
        *(float4*)&b[0] = *(const float4*)&Bs[k][n0];
        *(float4*)&b[4] = *(const float4*)&Bs[k][n0 + 4];
#pragma unroll
        for (int jr = 0; jr < 8; ++jr)
#pragma unroll
            for (int jc = 0; jc < 8; ++jc)
                acc[jr][jc] += a[jr] * b[jc];
    }
#pragma unroll
    for (int jr = 0; jr < 8; ++jr) {
        const size_t off = (size_t)(rBase + r0 + jr) * 4096 + nBase + n0;
        *(float4*)(out + off) = make_float4(acc[jr][0], acc[jr][1], acc[jr][2], acc[jr][3]);
        *(float4*)(out + off + 4) = make_float4(acc[jr][4], acc[jr][5], acc[jr][6], acc[jr][7]);
    }
}

extern "C" void kernel_launch(void* const* d_in, const int* in_sizes, int n_in,
                              void* d_out, int out_size, void* d_ws, size_t ws_size,
                              hipStream_t stream) {
    const float* x = (const float*)d_in[0];   // (64,128,4096)
    const float* w = (const float*)d_in[1];   // (128,128,64)
    float* out = (float*)d_out;               // (64,128,4096)
    float* wsf = (float*)d_ws;

    float* MrT     = wsf;              // [4096][64]  1 MB
    float* Mc      = wsf + 262144;     // [4096][64]  1 MB
    float* xh_t    = wsf + 524288;     // [64][8192]  2 MB
    float* wp      = wsf + 1048576;    // [64][128][128] 4 MB
    float* wm      = wsf + 2097152;    // [64][128][128] 4 MB
    float* mixed_t = wsf + 3145728;    // [64][8192]  2 MB

    hipMemsetAsync(xh_t, 0, 524288 * sizeof(float), stream);
    hipMemsetAsync(mixed_t, 0, 524288 * sizeof(float), stream);

    matgen<<<dim3(4096), dim3(64), 0, stream>>>(MrT, Mc);
    wtrans<<<dim3(128, 64), dim3(128), 0, stream>>>(w, wp, wm);
    passA<<<dim3(64, 8), dim3(256), 0, stream>>>(x, MrT, xh_t);
    passB<<<dim3(4, 64), dim3(256), 0, stream>>>(xh_t, wp, wm, mixed_t);
    passC<<<dim3(32, 64), dim3(256), 0, stream>>>(mixed_t, Mc, out);
}

// Round 2
// 470.030 us; speedup vs baseline: 1.0237x; 1.0237x over previous
//
#include <hip/hip_runtime.h>
#include <math.h>

#define PI2F 6.28318530717958647692f

// M[r,c] of the 4096-point naive-cas "FHT" operator defined by the reference
// recursion. Bit l of c selects the odd branch at level l (size 4096>>l).
__device__ __forceinline__ float mval(int r, int c) {
    float prod = 1.0f;
    int m = r;
#pragma unroll
    for (int l = 0; l < 12; ++l) {
        const int nl = 4096 >> l;
        const int half = nl >> 1;
        float sign = 1.0f;
        if (m >= half) { m -= half; sign = -1.0f; }
        if ((c >> l) & 1) {
            float th = (PI2F / (float)nl) * (float)m;
            float s, cc;
            sincosf(th, &s, &cc);
            prod *= sign * (cc + s);
        }
    }
    return prod;
}

// MrT[j][m] = M[m][j]  (analysis, m<64), McT[m][n] = M[n][m]/4096 (synthesis, transposed)
__global__ void matgen(float* __restrict__ MrT, float* __restrict__ McT) {
    const int j = blockIdx.x;    // 0..4095
    const int m = threadIdx.x;   // 0..63
    MrT[j * 64 + m] = mval(m, j);
    McT[(size_t)m * 4096 + j] = mval(j, m) * (1.0f / 4096.0f);
}

// wp[m][i][o] = 0.5*(w[i][o][m] + w[i][o][m']), wm = 0.5*(w - w'), m'=(64-m)%64
__global__ void wtrans(const float* __restrict__ w,
                       float* __restrict__ wp, float* __restrict__ wm) {
    const int i = blockIdx.x;    // 0..127
    const int m = blockIdx.y;    // 0..63
    const int o = threadIdx.x;   // 0..127
    const int mp = (64 - m) & 63;
    const float a = w[(i * 128 + o) * 64 + m];
    const float b = w[(i * 128 + o) * 64 + mp];
    wp[((size_t)m * 128 + i) * 128 + o] = 0.5f * (a + b);
    wm[((size_t)m * 128 + i) * 128 + o] = 0.5f * (a - b);
}

// Pass A: xh_t[m][row] += sum_j X[row][j] * MrT[j][m], row=(b*128+i)
// Tile 128 rows x 64 m, K-slice 512 (grid 64 x 8). Thread = 8 rows x 4 m.
// tr = tid>>4 so a-reads are broadcast (conflict-free); Ms reads 2-way (free).
__global__ __launch_bounds__(256) void passA(const float* __restrict__ X,
                                             const float* __restrict__ MrT,
                                             float* __restrict__ xh_t) {
    __shared__ float Xs[64 * 132];  // [k][row], stride 132 (=4 mod 32, 16B-aligned rows)
    __shared__ float Ms[64 * 64];   // [k][m]
    const int tid = threadIdx.x;
    const int rBase = blockIdx.x * 128;
    const int kSlice = blockIdx.y * 512;
    const int tm = tid & 15;        // m-group
    const int tr = tid >> 4;        // row-group (per-wave: 4 consecutive values)
    const int m0 = 4 * tm;
    const int r0 = 8 * tr;

    float acc[8][4];
#pragma unroll
    for (int a = 0; a < 8; ++a)
#pragma unroll
        for (int b = 0; b < 4; ++b) acc[a][b] = 0.0f;

    for (int ch = 0; ch < 8; ++ch) {
        const int kc = kSlice + ch * 64;
        // stage X tile (128 rows x 64 k), transposed into Xs[k][row]
#pragma unroll
        for (int it = 0; it < 8; ++it) {
            const int slot = tid + it * 256;        // 2048 float4 slots
            const int row = slot >> 4;
            const int j4 = slot & 15;
            const float4 v = *(const float4*)(X + (size_t)(rBase + row) * 4096 + kc + 4 * j4);
            Xs[(4 * j4 + 0) * 132 + row] = v.x;
            Xs[(4 * j4 + 1) * 132 + row] = v.y;
            Xs[(4 * j4 + 2) * 132 + row] = v.z;
            Xs[(4 * j4 + 3) * 132 + row] = v.w;
        }
        // stage M tile (64 k x 64 m), direct copy
#pragma unroll
        for (int it = 0; it < 4; ++it) {
            const int slot = tid + it * 256;        // 1024 float4 slots
            const int k = slot >> 4;
            const int m4 = slot & 15;
            *(float4*)&Ms[k * 64 + 4 * m4] =
                *(const float4*)(MrT + (size_t)(kc + k) * 64 + 4 * m4);
        }
        __syncthreads();
#pragma unroll 8
        for (int k = 0; k < 64; ++k) {
            float a[8], b[4];
            *(float4*)&a[0] = *(const float4*)&Xs[k * 132 + r0];
            *(float4*)&a[4] = *(const float4*)&Xs[k * 132 + r0 + 4];
            *(float4*)&b[0] = *(const float4*)&Ms[k * 64 + m0];
#pragma unroll
            for (int jr = 0; jr < 8; ++jr)
#pragma unroll
                for (int jm = 0; jm < 4; ++jm)
                    acc[jr][jm] += a[jr] * b[jm];
        }
        __syncthreads();
    }
#pragma unroll
    for (int jm = 0; jm < 4; ++jm)
#pragma unroll
        for (int jr = 0; jr < 8; ++jr)
            atomicAdd(&xh_t[(size_t)(m0 + jm) * 8192 + rBase + r0 + jr], acc[jr][jm]);
}

// Pass B: mixed_t[m][b*128+o] = sum_i Us[b][i]*wp[m][i][o] + Uns[b][i]*wm[m][i][o]
__global__ __launch_bounds__(256) void passB(const float* __restrict__ xh_t,
                                             const float* __restrict__ wp,
                                             const float* __restrict__ wm,
                                             float* __restrict__ mixed_t) {
    __shared__ float Us[64][33];
    __shared__ float Uns[64][33];
    const int tid = threadIdx.x;
    const int m = blockIdx.y;
    const int iBase = blockIdx.x * 32;
    const int mp = (64 - m) & 63;
#pragma unroll
    for (int it = 0; it < 2; ++it) {
        const int slot = tid + it * 256;   // 512 float4 slots
        const int b = slot >> 3;
        const int i4 = slot & 7;
        const float4 vu = *(const float4*)(xh_t + (size_t)m * 8192 + b * 128 + iBase + 4 * i4);
        const float4 vn = *(const float4*)(xh_t + (size_t)mp * 8192 + b * 128 + iBase + 4 * i4);
        Us[b][i4 * 4 + 0] = vu.x; Us[b][i4 * 4 + 1] = vu.y;
        Us[b][i4 * 4 + 2] = vu.z; Us[b][i4 * 4 + 3] = vu.w;
        Uns[b][i4 * 4 + 0] = vn.x; Uns[b][i4 * 4 + 1] = vn.y;
        Uns[b][i4 * 4 + 2] = vn.z; Uns[b][i4 * 4 + 3] = vn.w;
    }
    __syncthreads();
    const int o0 = (tid & 15) * 8;
    const int b0 = (tid >> 4) * 4;
    float acc[4][8];
#pragma unroll
    for (int a = 0; a < 4; ++a)
#pragma unroll
        for (int b = 0; b < 8; ++b) acc[a][b] = 0.0f;

    for (int i = 0; i < 32; ++i) {
        const int ig = iBase + i;
        float p[8], q[8];
        *(float4*)&p[0] = *(const float4*)(wp + ((size_t)m * 128 + ig) * 128 + o0);
        *(float4*)&p[4] = *(const float4*)(wp + ((size_t)m * 128 + ig) * 128 + o0 + 4);
        *(float4*)&q[0] = *(const float4*)(wm + ((size_t)m * 128 + ig) * 128 + o0);
        *(float4*)&q[4] = *(const float4*)(wm + ((size_t)m * 128 + ig) * 128 + o0 + 4);
#pragma unroll
        for (int jb = 0; jb < 4; ++jb) {
            const float u = Us[b0 + jb][i];
            const float un = Uns[b0 + jb][i];
#pragma unroll
            for (int jo = 0; jo < 8; ++jo)
                acc[jb][jo] += u * p[jo] + un * q[jo];
        }
    }
#pragma unroll
    for (int jb = 0; jb < 4; ++jb)
#pragma unroll
        for (int jo = 0; jo < 8; ++jo)
            atomicAdd(&mixed_t[(size_t)m * 8192 + (b0 + jb) * 128 + o0 + jo], acc[jb][jo]);
}

// Pass C: out[row][n] = sum_{m<64} mixed_t[m][row] * McT[m][n]   (1/4096 folded in)
// Tile 64 rows x 128 n, K=64 full. Thread = 4 rows x (4+4) n split +-64.
// No LDS transpose anywhere: both As and Bs are direct b128 copies.
__global__ __launch_bounds__(256) void passC(const float* __restrict__ mixed_t,
                                             const float* __restrict__ McT,
                                             float* __restrict__ out) {
    __shared__ float As[64 * 64];    // [m][row]
    __shared__ float Bs[64 * 132];   // [m][n], stride 132
    const int tid = threadIdx.x;
    const int nBase = blockIdx.x * 128;
    const int rBase = blockIdx.y * 64;
#pragma unroll
    for (int it = 0; it < 4; ++it) {
        const int slot = tid + it * 256;     // 1024 float4 slots
        const int m = slot >> 4;
        const int r4 = slot & 15;
        *(float4*)&As[m * 64 + 4 * r4] =
            *(const float4*)(mixed_t + (size_t)m * 8192 + rBase + 4 * r4);
    }
#pragma unroll
    for (int it = 0; it < 8; ++it) {
        const int slot = tid + it * 256;     // 2048 float4 slots
        const int m = slot >> 5;
        const int j = slot & 31;
        *(float4*)&Bs[m * 132 + 4 * j] =
            *(const float4*)(McT + (size_t)m * 4096 + nBase + 4 * j);
    }
    __syncthreads();
    const int tn = tid & 15;
    const int tr = tid >> 4;     // per-wave: 4 consecutive values -> broadcast a-reads
    const int r0 = 4 * tr;

    float acc[4][8];
#pragma unroll
    for (int a = 0; a < 4; ++a)
#pragma unroll
        for (int b = 0; b < 8; ++b) acc[a][b] = 0.0f;

#pragma unroll 8
    for (int k = 0; k < 64; ++k) {
        float a[4], b[8];
        *(float4*)&a[0] = *(const float4*)&As[k * 64 + r0];
        *(float4*)&b[0] = *(const float4*)&Bs[k * 132 + 4 * tn];
        *(float4*)&b[4] = *(const float4*)&Bs[k * 132 + 64 + 4 * tn];
#pragma unroll
        for (int jr = 0; jr < 4; ++jr)
#pragma unroll
            for (int jc = 0; jc < 8; ++jc)
                acc[jr][jc] += a[jr] * b[jc];
    }
#pragma unroll
    for (int jr = 0; jr < 4; ++jr) {
        const size_t off = (size_t)(rBase + r0 + jr) * 4096 + nBase;
        *(float4*)(out + off + 4 * tn) =
            make_float4(acc[jr][0], acc[jr][1], acc[jr][2], acc[jr][3]);
        *(float4*)(out + off + 64 + 4 * tn) =
            make_float4(acc[jr][4], acc[jr][5], acc[jr][6], acc[jr][7]);
    }
}

extern "C" void kernel_launch(void* const* d_in, const int* in_sizes, int n_in,
                              void* d_out, int out_size, void* d_ws, size_t ws_size,
                              hipStream_t stream) {
    const float* x = (const float*)d_in[0];   // (64,128,4096)
    const float* w = (const float*)d_in[1];   // (128,128,64)
    float* out = (float*)d_out;               // (64,128,4096)
    float* wsf = (float*)d_ws;

    float* MrT     = wsf;              // [4096][64]  1 MB
    float* McT     = wsf + 262144;     // [64][4096]  1 MB
    float* xh_t    = wsf + 524288;     // [64][8192]  2 MB
    float* wp      = wsf + 1048576;    // [64][128][128] 4 MB
    float* wm      = wsf + 2097152;    // [64][128][128] 4 MB
    float* mixed_t = wsf + 3145728;    // [64][8192]  2 MB

    hipMemsetAsync(xh_t, 0, 524288 * sizeof(float), stream);
    hipMemsetAsync(mixed_t, 0, 524288 * sizeof(float), stream);

    matgen<<<dim3(4096), dim3(64), 0, stream>>>(MrT, McT);
    wtrans<<<dim3(128, 64), dim3(128), 0, stream>>>(w, wp, wm);
    passA<<<dim3(64, 8), dim3(256), 0, stream>>>(x, MrT, xh_t);
    passB<<<dim3(4, 64), dim3(256), 0, stream>>>(xh_t, wp, wm, mixed_t);
    passC<<<dim3(32, 128), dim3(256), 0, stream>>>(mixed_t, McT, out);
}

// Round 3
// 326.085 us; speedup vs baseline: 1.4756x; 1.4414x over previous
//
#include <hip/hip_runtime.h>
#include <math.h>

#define PI2F 6.28318530717958647692f

__host__ __device__ constexpr int br6(int p) {
    return ((p & 1) << 5) | ((p & 2) << 3) | ((p & 4) << 1) |
           ((p & 8) >> 1) | ((p & 16) >> 3) | ((p & 32) >> 5);
}
__host__ __device__ constexpr int brN(int v, int bits) {
    int r = 0;
    for (int i = 0; i < bits; ++i) r |= ((v >> i) & 1) << (bits - 1 - i);
    return r;
}

// 64-pt naive-cas butterfly twiddles: cas(2*pi*k/s) (standard FFT-grid cas values)
__device__ static constexpr float CAS8T[4] = {1.f, 1.41421356f, 1.f, 0.f};
__device__ static constexpr float CAS16T[8] = {
    1.f, 1.30656296f, 1.41421356f, 1.30656296f, 1.f, 0.54119610f, 0.f, -0.54119610f};
__device__ static constexpr float CAS32T[16] = {
    1.f, 1.17587560f, 1.30656296f, 1.38703985f, 1.41421356f, 1.38703985f,
    1.30656296f, 1.17587560f, 1.f, 0.78569496f, 0.54119610f, 0.27589938f,
    0.f, -0.27589938f, -0.54119610f, -0.78569496f};
__device__ static constexpr float CAS64T[32] = {
    1.f, 1.09320187f, 1.17587560f, 1.24722502f, 1.30656296f, 1.35331800f,
    1.38703985f, 1.40740373f, 1.41421356f, 1.40740373f, 1.38703985f,
    1.35331800f, 1.30656296f, 1.24722502f, 1.17587560f, 1.09320187f,
    1.f, 0.89716759f, 0.78569496f, 0.66665566f, 0.54119610f, 0.41052452f,
    0.27589938f, 0.13861717f, 0.f, -0.13861717f, -0.27589938f, -0.41052452f,
    -0.54119610f, -0.66665566f, -0.78569496f, -0.89716759f};

// casA[l][r] = cas(2*pi*r/(4096>>l)), l=0..5 (analysis combine factors, r<64 => "+" path)
// casT[j][c] = cas(2*pi*(c+64u)/(4096>>l)) for j -> (l,u): l=5:j=0; l=4:j in[1,3); l=3:[3,7);
//             l=2:[7,15); l=1:[15,31); l=0:[31,63)   (synthesis expansion factors)
__global__ void casgen(float* __restrict__ casA, float* __restrict__ casT) {
    const int r = threadIdx.x;
    const int g = blockIdx.x;
    float s, c;
    if (g < 6) {
        sincosf(PI2F * (float)r / (float)(4096 >> g), &s, &c);
        casA[g * 64 + r] = c + s;
    } else {
        const int j = g - 6;
        int l, u;
        if (j == 0) { l = 5; u = 0; }
        else if (j < 3) { l = 4; u = j - 1; }
        else if (j < 7) { l = 3; u = j - 3; }
        else if (j < 15) { l = 2; u = j - 7; }
        else if (j < 31) { l = 1; u = j - 15; }
        else { l = 0; u = j - 31; }
        sincosf(PI2F * (float)(r + 64 * u) / (float)(4096 >> l), &s, &c);
        casT[j * 64 + r] = c + s;
    }
}

// wp[m][i][o] = 0.5*(w[i][o][m] + w[i][o][m']), wm = 0.5*(w - w'), m'=(64-m)%64
__global__ void wtrans(const float* __restrict__ w,
                       float* __restrict__ wp, float* __restrict__ wm) {
    const int i = blockIdx.x;
    const int m = blockIdx.y;
    const int o = threadIdx.x;
    const int mp = (64 - m) & 63;
    const float a = w[(i * 128 + o) * 64 + m];
    const float b = w[(i * 128 + o) * 64 + mp];
    wp[((size_t)m * 128 + i) * 128 + o] = 0.5f * (a + b);
    wm[((size_t)m * 128 + i) * 128 + o] = 0.5f * (a - b);
}

// Analysis: xh_t[r][row] = sum_c G[r,c] * y_c[r];  y_c = T64 over t of x[row, 64t+c].
// One wave per block; lane=c for load/butterfly, lane=r after LDS transpose.
__global__ __launch_bounds__(64) void fht_fwd(const float* __restrict__ x,
                                              const float* __restrict__ casA,
                                              float* __restrict__ xh_t) {
    __shared__ float Y[64 * 65];
    const int lane = threadIdx.x;

    float a6[6];
#pragma unroll
    for (int l = 0; l < 6; ++l) a6[l] = casA[l * 64 + lane];
    float G[64];
    G[0] = 1.0f;
#pragma unroll
    for (int c = 1; c < 64; ++c) G[c] = G[c & (c - 1)] * a6[__builtin_ctz(c)];

    const int row0 = blockIdx.x * 2;
#pragma unroll 1
    for (int rr = 0; rr < 2; ++rr) {
        const int row = row0 + rr;
        const float* xr = x + (size_t)row * 4096 + lane;
        float v[64];
#pragma unroll
        for (int p = 0; p < 64; ++p) v[p] = xr[64 * br6(p)];

        // 64-pt naive-cas DIT butterfly (input bit-reversed in t)
#pragma unroll
        for (int b = 0; b < 64; b += 2) {
            float t0 = v[b], t1 = v[b + 1];
            v[b] = t0 + t1; v[b + 1] = t0 - t1;
        }
#pragma unroll
        for (int b = 0; b < 64; b += 4)
#pragma unroll
            for (int k = 0; k < 2; ++k) {
                float t0 = v[b + k], t1 = v[b + k + 2];
                v[b + k] = t0 + t1; v[b + k + 2] = t0 - t1;
            }
#pragma unroll
        for (int b = 0; b < 64; b += 8)
#pragma unroll
            for (int k = 0; k < 4; ++k) {
                float w = CAS8T[k];
                float t0 = v[b + k], t1 = v[b + k + 4];
                v[b + k] = fmaf(w, t1, t0); v[b + k + 4] = fmaf(-w, t1, t0);
            }
#pragma unroll
        for (int b = 0; b < 64; b += 16)
#pragma unroll
            for (int k = 0; k < 8; ++k) {
                float w = CAS16T[k];
                float t0 = v[b + k], t1 = v[b + k + 8];
                v[b + k] = fmaf(w, t1, t0); v[b + k + 8] = fmaf(-w, t1, t0);
            }
#pragma unroll
        for (int b = 0; b < 64; b += 32)
#pragma unroll
            for (int k = 0; k < 16; ++k) {
                float w = CAS32T[k];
                float t0 = v[b + k], t1 = v[b + k + 16];
                v[b + k] = fmaf(w, t1, t0); v[b + k + 16] = fmaf(-w, t1, t0);
            }
#pragma unroll
        for (int k = 0; k < 32; ++k) {
            float w = CAS64T[k];
            float t0 = v[k], t1 = v[k + 32];
            v[k] = fmaf(w, t1, t0); v[k + 32] = fmaf(-w, t1, t0);
        }

        // transpose via LDS: lane c writes y_c[m]; lane r reads y_c[r]
#pragma unroll
        for (int m = 0; m < 64; ++m) Y[lane * 65 + m] = v[m];
        __syncthreads();
        float acc = 0.0f;
#pragma unroll
        for (int c = 0; c < 64; ++c) acc = fmaf(G[c], Y[c * 65 + lane], acc);
        __syncthreads();
        xh_t[(size_t)lane * 8192 + row] = acc;   // scatter; L2-merged (2 MB region)
    }
}

// Pass B (unchanged structure): mixed_t[m][row_o] via wp/wm GEMM with i-slice atomics
__global__ __launch_bounds__(256) void passB(const float* __restrict__ xh_t,
                                             const float* __restrict__ wp,
                                             const float* __restrict__ wm,
                                             float* __restrict__ mixed_t) {
    __shared__ float Us[64][33];
    __shared__ float Uns[64][33];
    const int tid = threadIdx.x;
    const int m = blockIdx.y;
    const int iBase = blockIdx.x * 32;
    const int mp = (64 - m) & 63;
#pragma unroll
    for (int it = 0; it < 2; ++it) {
        const int slot = tid + it * 256;
        const int b = slot >> 3;
        const int i4 = slot & 7;
        const float4 vu = *(const float4*)(xh_t + (size_t)m * 8192 + b * 128 + iBase + 4 * i4);
        const float4 vn = *(const float4*)(xh_t + (size_t)mp * 8192 + b * 128 + iBase + 4 * i4);
        Us[b][i4 * 4 + 0] = vu.x; Us[b][i4 * 4 + 1] = vu.y;
        Us[b][i4 * 4 + 2] = vu.z; Us[b][i4 * 4 + 3] = vu.w;
        Uns[b][i4 * 4 + 0] = vn.x; Uns[b][i4 * 4 + 1] = vn.y;
        Uns[b][i4 * 4 + 2] = vn.z; Uns[b][i4 * 4 + 3] = vn.w;
    }
    __syncthreads();
    const int o0 = (tid & 15) * 8;
    const int b0 = (tid >> 4) * 4;
    float acc[4][8];
#pragma unroll
    for (int a = 0; a < 4; ++a)
#pragma unroll
        for (int b = 0; b < 8; ++b) acc[a][b] = 0.0f;

    for (int i = 0; i < 32; ++i) {
        const int ig = iBase + i;
        float p[8], q[8];
        *(float4*)&p[0] = *(const float4*)(wp + ((size_t)m * 128 + ig) * 128 + o0);
        *(float4*)&p[4] = *(const float4*)(wp + ((size_t)m * 128 + ig) * 128 + o0 + 4);
        *(float4*)&q[0] = *(const float4*)(wm + ((size_t)m * 128 + ig) * 128 + o0);
        *(float4*)&q[4] = *(const float4*)(wm + ((size_t)m * 128 + ig) * 128 + o0 + 4);
#pragma unroll
        for (int jb = 0; jb < 4; ++jb) {
            const float u = Us[b0 + jb][i];
            const float un = Uns[b0 + jb][i];
#pragma unroll
            for (int jo = 0; jo < 8; ++jo)
                acc[jb][jo] += u * p[jo] + un * q[jo];
        }
    }
#pragma unroll
    for (int jb = 0; jb < 4; ++jb)
#pragma unroll
        for (int jo = 0; jo < 8; ++jo)
            atomicAdd(&mixed_t[(size_t)m * 8192 + (b0 + jb) * 128 + o0 + jo], acc[jb][jo]);
}

// Synthesis: out[row, 64t+c] = sum_{m<64} M[n,m]*mixed[row,m]/4096, fully within-lane
// (lane = c = n mod 64) via 6-level doubling tree with per-lane K table.
__global__ __launch_bounds__(64) void fht_inv(const float* __restrict__ mixed_t,
                                              const float* __restrict__ casT,
                                              float* __restrict__ out) {
    __shared__ __align__(16) float S[64];
    const int lane = threadIdx.x;
    float K[63];
#pragma unroll
    for (int j = 0; j < 63; ++j) K[j] = casT[j * 64 + lane];

    const int row0 = blockIdx.x * 4;
#pragma unroll 1
    for (int rr = 0; rr < 4; ++rr) {
        const int row = row0 + rr;
        const float mv = mixed_t[(size_t)lane * 8192 + row] * (1.0f / 4096.0f);
        __syncthreads();
        S[lane] = mv;
        __syncthreads();
        float e[64];
#pragma unroll
        for (int m4 = 0; m4 < 16; ++m4) {
            const float4 q = *(const float4*)&S[4 * m4];   // LDS broadcast
            e[4 * m4 + 0] = q.x; e[4 * m4 + 1] = q.y;
            e[4 * m4 + 2] = q.z; e[4 * m4 + 3] = q.w;
        }
        // level 5 (m bit5, K[0])
#pragma unroll
        for (int mp = 0; mp < 32; ++mp) {
            float w = K[0];
            float t0 = e[mp], t1 = e[mp + 32];
            e[mp] = fmaf(w, t1, t0); e[mp + 32] = fmaf(-w, t1, t0);
        }
        // level 4
#pragma unroll
        for (int hi = 0; hi < 2; ++hi)
#pragma unroll
            for (int mp = 0; mp < 16; ++mp) {
                float w = K[1 + brN(hi, 1)];
                int i0 = hi * 32 + mp;
                float t0 = e[i0], t1 = e[i0 + 16];
                e[i0] = fmaf(w, t1, t0); e[i0 + 16] = fmaf(-w, t1, t0);
            }
        // level 3
#pragma unroll
        for (int hi = 0; hi < 4; ++hi)
#pragma unroll
            for (int mp = 0; mp < 8; ++mp) {
                float w = K[3 + brN(hi, 2)];
                int i0 = hi * 16 + mp;
                float t0 = e[i0], t1 = e[i0 + 8];
                e[i0] = fmaf(w, t1, t0); e[i0 + 8] = fmaf(-w, t1, t0);
            }
        // level 2
#pragma unroll
        for (int hi = 0; hi < 8; ++hi)
#pragma unroll
            for (int mp = 0; mp < 4; ++mp) {
                float w = K[7 + brN(hi, 3)];
                int i0 = hi * 8 + mp;
                float t0 = e[i0], t1 = e[i0 + 4];
                e[i0] = fmaf(w, t1, t0); e[i0 + 4] = fmaf(-w, t1, t0);
            }
        // level 1
#pragma unroll
        for (int hi = 0; hi < 16; ++hi)
#pragma unroll
            for (int mp = 0; mp < 2; ++mp) {
                float w = K[15 + brN(hi, 4)];
                int i0 = hi * 4 + mp;
                float t0 = e[i0], t1 = e[i0 + 2];
                e[i0] = fmaf(w, t1, t0); e[i0 + 2] = fmaf(-w, t1, t0);
            }
        // level 0
#pragma unroll
        for (int hi = 0; hi < 32; ++hi) {
            float w = K[31 + brN(hi, 5)];
            int i0 = hi * 2;
            float t0 = e[i0], t1 = e[i0 + 1];
            e[i0] = fmaf(w, t1, t0); e[i0 + 1] = fmaf(-w, t1, t0);
        }
        float* outr = out + (size_t)row * 4096 + lane;
#pragma unroll
        for (int t = 0; t < 64; ++t) outr[64 * t] = e[br6(t)];
    }
}

extern "C" void kernel_launch(void* const* d_in, const int* in_sizes, int n_in,
                              void* d_out, int out_size, void* d_ws, size_t ws_size,
                              hipStream_t stream) {
    const float* x = (const float*)d_in[0];   // (64,128,4096)
    const float* w = (const float*)d_in[1];   // (128,128,64)
    float* out = (float*)d_out;               // (64,128,4096)
    float* wsf = (float*)d_ws;

    float* casA    = wsf;              // 384 floats
    float* casT    = wsf + 512;        // 4032 floats
    float* xh_t    = wsf + 8192;       // [64][8192]  2 MB
    float* wp      = wsf + 532480;     // [64][128][128] 4 MB
    float* wm      = wsf + 1581056;    // 4 MB
    float* mixed_t = wsf + 2629632;    // [64][8192]  2 MB

    hipMemsetAsync(mixed_t, 0, 524288 * sizeof(float), stream);

    casgen<<<dim3(69), dim3(64), 0, stream>>>(casA, casT);
    wtrans<<<dim3(128, 64), dim3(128), 0, stream>>>(w, wp, wm);
    fht_fwd<<<dim3(4096), dim3(64), 0, stream>>>(x, casA, xh_t);
    passB<<<dim3(4, 64), dim3(256), 0, stream>>>(xh_t, wp, wm, mixed_t);
    fht_inv<<<dim3(2048), dim3(64), 0, stream>>>(mixed_t, casT, out);
}